// Round 3
// baseline (1012.606 us; speedup 1.0000x reference)
//
#include <hip/hip_runtime.h>
#include <hip/hip_bf16.h>
#include <cstdint>

#define HD 256
#define NHEADS 8
#define NB 256
#define SL 64
#define NN 16384
#define NE 131072
#define NTOT (NE + NN)   // 147456

typedef float floatx4 __attribute__((ext_vector_type(4)));
typedef short shortx8 __attribute__((ext_vector_type(8)));
typedef unsigned short ushortx8 __attribute__((ext_vector_type(8)));
typedef unsigned short ushortx4 __attribute__((ext_vector_type(4)));

__device__ __forceinline__ unsigned short f2bf(float f) {
    union { float f; unsigned u; } a; a.f = f;
    unsigned r = a.u + 0x7fffu + ((a.u >> 16) & 1u);
    return (unsigned short)(r >> 16);
}
__device__ __forceinline__ float bf2f(unsigned short b) {
    union { unsigned u; float f; } a; a.u = ((unsigned)b) << 16;
    return a.f;
}

// ---------------- conversions ----------------

__global__ void k_cast_bf16(const float* __restrict__ in, unsigned short* __restrict__ out, int n4) {
    int i = blockIdx.x * 256 + threadIdx.x;
    if (i >= n4) return;
    float4 v = ((const float4*)in)[i];
    ushortx4 o;
    o[0] = f2bf(v.x); o[1] = f2bf(v.y); o[2] = f2bf(v.z); o[3] = f2bf(v.w);
    *(ushortx4*)&out[i * 4] = o;
}

// out[n][k] = bf16(in[k][n]); in is K x N fp32. grid (N/32, K/32), block (32,8)
__global__ void k_transpose_bf16(const float* __restrict__ in, unsigned short* __restrict__ out,
                                 int K, int N) {
    __shared__ float t[32][33];
    int nb = blockIdx.x * 32, kb = blockIdx.y * 32;
    int tx = threadIdx.x, ty = threadIdx.y;
#pragma unroll
    for (int i = 0; i < 4; ++i) {
        int k = kb + ty + i * 8;
        t[ty + i * 8][tx] = in[(size_t)k * N + nb + tx];
    }
    __syncthreads();
#pragma unroll
    for (int i = 0; i < 4; ++i) {
        int nrow = nb + ty + i * 8;
        out[(size_t)nrow * K + kb + tx] = f2bf(t[tx][ty + i * 8]);
    }
}

__global__ void k_add2(const float* __restrict__ a, const float* __restrict__ b,
                       float* __restrict__ o, int n) {
    int i = blockIdx.x * 256 + threadIdx.x;
    if (i < n) o[i] = a[i] + b[i];
}

// x_b[n][d] = bf16(emb[x_ids[n]][d]), row 0 of emb forced to 0
__global__ void k_gather_x(const int* __restrict__ ids, const float* __restrict__ emb,
                           unsigned short* __restrict__ xb) {
    int i = blockIdx.x * 256 + threadIdx.x;   // over NN*64
    int n = i >> 6, d4 = (i & 63) << 2;
    int id = ids[n];
    float4 v = make_float4(0.f, 0.f, 0.f, 0.f);
    if (id != 0) v = *(const float4*)&emb[(size_t)id * HD + d4];
    ushortx4 o;
    o[0] = f2bf(v.x); o[1] = f2bf(v.y); o[2] = f2bf(v.z); o[3] = f2bf(v.w);
    *(ushortx4*)&xb[(size_t)n * HD + d4] = o;
}

// ---------------- GEMM: C(MxN) = A(MxK bf16) * B^T  (B given as N x K bf16) ----------------

template <bool OUT_BF16, bool HAS_BIAS>
__global__ __launch_bounds__(256, 2) void k_gemm_bt(
    const unsigned short* __restrict__ A, const unsigned short* __restrict__ B,
    void* __restrict__ C, const float* __restrict__ bias, int M, int Nn, int K) {
    constexpr int LDT = 56;
    __shared__ unsigned short As[128 * LDT];
    __shared__ unsigned short Bs[128 * LDT];
    int tid = threadIdx.x;
    int wave = tid >> 6, lane = tid & 63;
    int q = lane >> 4, c16 = lane & 15;
    long m0 = (long)blockIdx.x * 128;
    long n0 = (long)blockIdx.y * 128;
    int wm = (wave & 1) << 6, wn = (wave >> 1) << 6;
    floatx4 acc[4][4] = {};
    int lrow = tid >> 2;
    int lk = (tid & 3) << 3;
    const unsigned short* Arow0 = A + (m0 + lrow) * K + lk;
    const unsigned short* Arow1 = A + (m0 + 64 + lrow) * K + lk;
    long nb0 = n0 + lrow;      if (nb0 >= Nn) nb0 = Nn - 1;
    long nb1 = n0 + 64 + lrow; if (nb1 >= Nn) nb1 = Nn - 1;
    const unsigned short* Brow0 = B + nb0 * K + lk;
    const unsigned short* Brow1 = B + nb1 * K + lk;

    for (int k0 = 0; k0 < K; k0 += 32) {
        ushortx8 a0 = *(const ushortx8*)(Arow0 + k0);
        ushortx8 a1 = *(const ushortx8*)(Arow1 + k0);
        ushortx8 b0 = *(const ushortx8*)(Brow0 + k0);
        ushortx8 b1 = *(const ushortx8*)(Brow1 + k0);
        __syncthreads();
        *(ushortx8*)&As[lrow * LDT + lk] = a0;
        *(ushortx8*)&As[(64 + lrow) * LDT + lk] = a1;
        *(ushortx8*)&Bs[lrow * LDT + lk] = b0;
        *(ushortx8*)&Bs[(64 + lrow) * LDT + lk] = b1;
        __syncthreads();
        shortx8 af[4], bfr[4];
#pragma unroll
        for (int mt = 0; mt < 4; ++mt)
            af[mt] = *(const shortx8*)&As[(wm + mt * 16 + c16) * LDT + q * 8];
#pragma unroll
        for (int nt = 0; nt < 4; ++nt)
            bfr[nt] = *(const shortx8*)&Bs[(wn + nt * 16 + c16) * LDT + q * 8];
#pragma unroll
        for (int mt = 0; mt < 4; ++mt)
#pragma unroll
            for (int nt = 0; nt < 4; ++nt)
                acc[mt][nt] = __builtin_amdgcn_mfma_f32_16x16x32_bf16(af[mt], bfr[nt], acc[mt][nt], 0, 0, 0);
    }
#pragma unroll
    for (int mt = 0; mt < 4; ++mt) {
        long row_base = m0 + wm + mt * 16 + q * 4;
#pragma unroll
        for (int nt = 0; nt < 4; ++nt) {
            long col = n0 + wn + nt * 16 + c16;
            if (col >= Nn) continue;
            float bv = HAS_BIAS ? bias[col] : 0.0f;
#pragma unroll
            for (int r = 0; r < 4; ++r) {
                float v = acc[mt][nt][r] + bv;
                long idx = (row_base + r) * (long)Nn + col;
                if (OUT_BF16) ((unsigned short*)C)[idx] = f2bf(v);
                else          ((float*)C)[idx] = v;
            }
        }
    }
}

// ---------------- attention dots ----------------

__global__ void k_alpha1(const unsigned short* __restrict__ h1b, const float* __restrict__ asrc,
                         const float* __restrict__ adst, float* __restrict__ als,
                         float* __restrict__ ald) {
    int n = blockIdx.x, t = threadIdx.x;
    ushortx8 hv = *(const ushortx8*)&h1b[(size_t)n * 2048 + t * 8];
    float s = 0.f, d = 0.f;
#pragma unroll
    for (int j = 0; j < 8; ++j) {
        float f = bf2f(hv[j]);
        s += f * asrc[t * 8 + j];
        d += f * adst[t * 8 + j];
    }
    for (int o = 16; o; o >>= 1) { s += __shfl_down(s, o, 32); d += __shfl_down(d, o, 32); }
    if ((t & 31) == 0) { als[n * 8 + (t >> 5)] = s; ald[n * 8 + (t >> 5)] = d; }
}

__global__ void k_alpha2(const unsigned short* __restrict__ x2b, const float* __restrict__ asrc,
                         const float* __restrict__ adst, float* __restrict__ als,
                         float* __restrict__ ald) {
    int n = blockIdx.x, t = threadIdx.x;
    ushortx4 hv = *(const ushortx4*)&x2b[(size_t)n * 256 + t * 4];
    float s = 0.f, d = 0.f;
#pragma unroll
    for (int j = 0; j < 4; ++j) {
        float f = bf2f(hv[j]);
        s += f * asrc[t * 4 + j];
        d += f * adst[t * 4 + j];
    }
    for (int o = 32; o; o >>= 1) { s += __shfl_down(s, o, 64); d += __shfl_down(d, o, 64); }
    if (t == 0) { als[n] = s; ald[n] = d; }
}

// ---------------- CSR build ----------------

__global__ void k_deg_init(int* __restrict__ deg) {
    int i = blockIdx.x * 256 + threadIdx.x;
    if (i < NN) deg[i] = 1;
}
__global__ void k_deg_count(const int* __restrict__ ei, int* __restrict__ deg) {
    int e = blockIdx.x * 256 + threadIdx.x;
    if (e < NE) atomicAdd(&deg[ei[NE + e]], 1);
}
__global__ void k_scan(const int* __restrict__ deg, int* __restrict__ row_start,
                       int* __restrict__ cursor) {
    __shared__ int s[1024];
    int t = threadIdx.x;
    int base = t * 16;
    int loc[16]; int sum = 0;
#pragma unroll
    for (int i = 0; i < 16; ++i) { loc[i] = deg[base + i]; sum += loc[i]; }
    s[t] = sum;
    __syncthreads();
    for (int o = 1; o < 1024; o <<= 1) {
        int v = (t >= o) ? s[t - o] : 0;
        __syncthreads();
        s[t] += v;
        __syncthreads();
    }
    int ex = s[t] - sum;
#pragma unroll
    for (int i = 0; i < 16; ++i) {
        row_start[base + i] = ex;
        cursor[base + i] = ex;
        ex += loc[i];
    }
    if (t == 0) row_start[NN] = NTOT;
}
__global__ void k_fill(const int* __restrict__ ei, int* __restrict__ cursor,
                       int* __restrict__ csr_src) {
    int e = blockIdx.x * 256 + threadIdx.x;
    if (e >= NTOT) return;
    int s, d;
    if (e < NE) { s = ei[e]; d = ei[NE + e]; }
    else        { s = e - NE; d = s; }
    int p = atomicAdd(&cursor[d], 1);
    csr_src[p] = s;
}

// ---------------- GAT aggregation ----------------

__global__ __launch_bounds__(256) void k_agg1(
    const int* __restrict__ row_start, const int* __restrict__ csr_src,
    const float* __restrict__ als, const float* __restrict__ ald,
    const unsigned short* __restrict__ h1b, const float* __restrict__ b1,
    unsigned short* __restrict__ out1b) {
    int n = blockIdx.x, t = threadIdx.x;
    int rs = row_start[n];
    int deg = row_start[n + 1] - rs;
    __shared__ float sm[8], sz[8], sad[8];
    if (t < 8) sad[t] = ald[n * 8 + t];
    __syncthreads();
    int hh = t >> 5, ii = t & 31;
    float adh = sad[hh];
    float lm = -1e30f;
    for (int i = ii; i < deg; i += 32) {
        int s = csr_src[rs + i];
        float e = als[s * 8 + hh] + adh;
        e = e >= 0.f ? e : 0.2f * e;
        lm = fmaxf(lm, e);
    }
    for (int o = 16; o; o >>= 1) lm = fmaxf(lm, __shfl_down(lm, o, 32));
    if (ii == 0) sm[hh] = lm;
    __syncthreads();
    float mh = sm[hh];
    float lz = 0.f;
    for (int i = ii; i < deg; i += 32) {
        int s = csr_src[rs + i];
        float e = als[s * 8 + hh] + adh;
        e = e >= 0.f ? e : 0.2f * e;
        lz += expf(e - mh);
    }
    for (int o = 16; o; o >>= 1) lz += __shfl_down(lz, o, 32);
    if (ii == 0) sz[hh] = lz;
    __syncthreads();
    float inv_z = 1.0f / (sz[hh] + 1e-16f);
    float acc[8] = {0.f, 0.f, 0.f, 0.f, 0.f, 0.f, 0.f, 0.f};
    for (int i = 0; i < deg; ++i) {
        int s = csr_src[rs + i];
        float e = als[s * 8 + hh] + adh;
        e = e >= 0.f ? e : 0.2f * e;
        float w = expf(e - mh) * inv_z;
        ushortx8 hv = *(const ushortx8*)&h1b[(size_t)s * 2048 + t * 8];
#pragma unroll
        for (int j = 0; j < 8; ++j) acc[j] += w * bf2f(hv[j]);
    }
    ushortx8 o8;
#pragma unroll
    for (int j = 0; j < 8; ++j) {
        float v = acc[j] + b1[t * 8 + j];
        v = v > 0.f ? v : expm1f(v);
        o8[j] = f2bf(v);
    }
    *(ushortx8*)&out1b[(size_t)n * 2048 + t * 8] = o8;
}

__global__ void k_agg2(const int* __restrict__ row_start, const int* __restrict__ csr_src,
                       const float* __restrict__ als, const float* __restrict__ ald,
                       const unsigned short* __restrict__ x2b, const float* __restrict__ b2,
                       unsigned short* __restrict__ out2b) {
    int n = blockIdx.x, t = threadIdx.x;
    int rs = row_start[n];
    int deg = row_start[n + 1] - rs;
    float adn = ald[n];
    float lm = -1e30f;
    for (int i = t; i < deg; i += 64) {
        float e = als[csr_src[rs + i]] + adn;
        e = e >= 0.f ? e : 0.2f * e;
        lm = fmaxf(lm, e);
    }
    for (int o = 32; o; o >>= 1) lm = fmaxf(lm, __shfl_down(lm, o, 64));
    float mh = __shfl(lm, 0, 64);
    float lz = 0.f;
    for (int i = t; i < deg; i += 64) {
        float e = als[csr_src[rs + i]] + adn;
        e = e >= 0.f ? e : 0.2f * e;
        lz += expf(e - mh);
    }
    for (int o = 32; o; o >>= 1) lz += __shfl_down(lz, o, 64);
    float zz = __shfl(lz, 0, 64);
    float inv_z = 1.0f / (zz + 1e-16f);
    float acc[4] = {0.f, 0.f, 0.f, 0.f};
    for (int i = 0; i < deg; ++i) {
        int s = csr_src[rs + i];
        float e = als[s] + adn;
        e = e >= 0.f ? e : 0.2f * e;
        float w = expf(e - mh) * inv_z;
        ushortx4 hv = *(const ushortx4*)&x2b[(size_t)s * 256 + t * 4];
#pragma unroll
        for (int j = 0; j < 4; ++j) acc[j] += w * bf2f(hv[j]);
    }
    ushortx4 o4;
#pragma unroll
    for (int j = 0; j < 4; ++j) o4[j] = f2bf(acc[j] + b2[t * 4 + j]);
    *(ushortx4*)&out2b[(size_t)n * 256 + t * 4] = o4;
}

// ---------------- LSTM recurrence, v4: L2-streamed weights, deep pipeline ----------------
// Lesson from v1/v3: a 512-thread block forces 2 waves/SIMD => max 256 unified
// regs/wave, so 256-reg weight residency is structurally impossible; the RA
// spilled (v3: WRITE_SIZE 3.5MB scratch) or re-streamed serially (v1: ~64 dependent
// L2 loads/step ~= 14.6k cycles/step). So: DON'T fight for residency. Whh (512KB)
// is L2-resident by construction; the fix is outstanding-load parallelism:
//   - 16 blocks x 1024 threads (16 waves = 4 waves/SIMD, 2x the TLP of v1),
//   - per wave: 16 h-cols x 4 gates = 32 MFMA/step, weights triple-buffered by
//     k-chunk (issue chunk k+3 right after consuming chunk k => 12 frags/48 regs
//     in flight/wave, x4 waves/SIMD ~= 12 loads in flight per SIMD),
//   - a-frags double-buffered from LDS, Xg issued at the top of the step.
// Register budget ~120 <= 128 cap at 4 waves/SIMD => no spill (verify:
// VGPR_Count<=128 AND WRITE_SIZE ~0.13MB). One barrier/step, LDS 17KB (h dbuf).

__global__ __launch_bounds__(1024, 1) void k_lstm4(const float* __restrict__ Xg,
                                                   const unsigned short* __restrict__ Whhb,
                                                   unsigned short* __restrict__ hTb) {
    __shared__ unsigned short hb2[2 * 16 * 264];   // double-buffered h, row stride 264 shorts

    int tid = threadIdx.x;
    int w = tid >> 6, lane = tid & 63;
    int q = lane >> 4, c16 = lane & 15;
    int r0 = blockIdx.x * 16;
    int wcol = w * 16 + c16;                       // h-col this lane's fragment column

    // per-gate weight row pointers: gate-col = g*256 + wcol, k-offset q*8
    const unsigned short* wp[4];
#pragma unroll
    for (int g = 0; g < 4; ++g)
        wp[g] = Whhb + (size_t)(g * 256 + wcol) * 256 + q * 8;

    for (int i = tid; i < 16 * 264; i += 1024) hb2[i] = 0;
    float cst[4] = {0.f, 0.f, 0.f, 0.f};
    __syncthreads();

    for (int t = 0; t < SL; ++t) {
        int p = t & 1;

        // Xg prefetch for this step (consumed in epilogue)
        float xg[4][4];
#pragma unroll
        for (int r = 0; r < 4; ++r) {
            const float* xp = Xg + ((size_t)(r0 + q * 4 + r) * SL + t) * 1024 + wcol;
#pragma unroll
            for (int g = 0; g < 4; ++g) xg[r][g] = xp[g * 256];
        }

        // weight stream: triple-buffered by k-chunk (4 frags per chunk, one per gate)
        shortx8 wb[3][4];
#pragma unroll
        for (int g = 0; g < 4; ++g) wb[0][g] = *(const shortx8*)(wp[g] + 0 * 32);
#pragma unroll
        for (int g = 0; g < 4; ++g) wb[1][g] = *(const shortx8*)(wp[g] + 1 * 32);
#pragma unroll
        for (int g = 0; g < 4; ++g) wb[2][g] = *(const shortx8*)(wp[g] + 2 * 32);

        floatx4 acc[4] = {};
        shortx8 af[2];
        af[0] = *(const shortx8*)&hb2[p * 4224 + c16 * 264 + q * 8];
#pragma unroll
        for (int k0 = 0; k0 < 8; ++k0) {
            if (k0 < 7)
                af[(k0 + 1) & 1] =
                    *(const shortx8*)&hb2[p * 4224 + c16 * 264 + (k0 + 1) * 32 + q * 8];
            shortx8 a = af[k0 & 1];
#pragma unroll
            for (int g = 0; g < 4; ++g)
                acc[g] = __builtin_amdgcn_mfma_f32_16x16x32_bf16(a, wb[k0 % 3][g], acc[g], 0, 0, 0);
            if (k0 + 3 < 8) {
#pragma unroll
                for (int g = 0; g < 4; ++g)
                    wb[k0 % 3][g] = *(const shortx8*)(wp[g] + (k0 + 3) * 32);
            }
        }

        // epilogue: gates -> c,h for rows q*4+r, h-col wcol
#pragma unroll
        for (int r = 0; r < 4; ++r) {
            float gi = acc[0][r] + xg[r][0];
            float gf = acc[1][r] + xg[r][1];
            float gg = acc[2][r] + xg[r][2];
            float go = acc[3][r] + xg[r][3];
            float si = __builtin_amdgcn_rcpf(1.f + __expf(-gi));
            float sf = __builtin_amdgcn_rcpf(1.f + __expf(-gf));
            float so = __builtin_amdgcn_rcpf(1.f + __expf(-go));
            float tg = 1.f - 2.f * __builtin_amdgcn_rcpf(1.f + __expf(2.f * gg));
            float c = sf * cst[r] + si * tg;
            cst[r] = c;
            float tc = 1.f - 2.f * __builtin_amdgcn_rcpf(1.f + __expf(2.f * c));
            hb2[(p ^ 1) * 4224 + (q * 4 + r) * 264 + wcol] = f2bf(so * tc);
        }
        __syncthreads();
    }
    // SL even -> final h is in buffer 0
    for (int i = tid; i < 16 * 256; i += 1024) {
        int row = i >> 8, col = i & 255;
        hTb[(size_t)(r0 + row) * 256 + col] = hb2[row * 264 + col];
    }
}

// ---------------- launch ----------------

extern "C" void kernel_launch(void* const* d_in, const int* in_sizes, int n_in,
                              void* d_out, int out_size, void* d_ws, size_t ws_size,
                              hipStream_t stream) {
    const int*   x_ids = (const int*)d_in[0];
    const int*   ei    = (const int*)d_in[1];
    const float* emb   = (const float*)d_in[3];
    const float* W1    = (const float*)d_in[4];
    const float* as1w  = (const float*)d_in[5];
    const float* ad1w  = (const float*)d_in[6];
    const float* b1    = (const float*)d_in[7];
    const float* W2    = (const float*)d_in[8];
    const float* as2w  = (const float*)d_in[9];
    const float* ad2w  = (const float*)d_in[10];
    const float* b2    = (const float*)d_in[11];
    const float* Wih   = (const float*)d_in[12];
    const float* Whh   = (const float*)d_in[13];
    const float* bih   = (const float*)d_in[14];
    const float* bhh   = (const float*)d_in[15];
    const float* Wp    = (const float*)d_in[16];
    const float* bp    = (const float*)d_in[17];

    char* ws = (char*)d_ws;
    size_t off = 0;
    auto alloc = [&](size_t bytes) -> void* {
        void* p = ws + off;
        off += (bytes + 255) & ~(size_t)255;
        return p;
    };
    unsigned short* h1b   = (unsigned short*)alloc((size_t)NN * 2048 * 2);  // reused as Xg
    float*          Xg    = (float*)h1b;
    unsigned short* out1b = (unsigned short*)alloc((size_t)NN * 2048 * 2);
    unsigned short* xb    = (unsigned short*)alloc((size_t)NN * 256 * 2);
    unsigned short* x2b   = (unsigned short*)alloc((size_t)NN * 256 * 2);
    unsigned short* out2b = (unsigned short*)alloc((size_t)NN * 256 * 2);
    unsigned short* W1t   = (unsigned short*)alloc((size_t)2048 * 256 * 2);
    unsigned short* W2t   = (unsigned short*)alloc((size_t)256 * 2048 * 2);
    unsigned short* Wihb  = (unsigned short*)alloc((size_t)1024 * 256 * 2);
    unsigned short* Whhb  = (unsigned short*)alloc((size_t)1024 * 256 * 2);
    unsigned short* Wpb   = (unsigned short*)alloc((size_t)37000 * 256 * 2);
    float*          bb    = (float*)alloc(1024 * 4);
    float*          als1  = (float*)alloc((size_t)NN * 8 * 4);
    float*          ald1  = (float*)alloc((size_t)NN * 8 * 4);
    float*          als2  = (float*)alloc((size_t)NN * 4);
    float*          ald2  = (float*)alloc((size_t)NN * 4);
    unsigned short* hTb   = (unsigned short*)alloc((size_t)256 * 256 * 2);
    int* deg       = (int*)alloc((size_t)NN * 4);
    int* row_start = (int*)alloc((size_t)(NN + 1) * 4);
    int* cursor    = (int*)alloc((size_t)NN * 4);
    int* csr_src   = (int*)alloc((size_t)NTOT * 4);
    (void)ws_size; (void)in_sizes; (void)n_in; (void)out_size;

    // weight prep
    k_transpose_bf16<<<dim3(2048 / 32, 256 / 32), dim3(32, 8), 0, stream>>>(W1, W1t, 256, 2048);
    k_transpose_bf16<<<dim3(256 / 32, 2048 / 32), dim3(32, 8), 0, stream>>>(W2, W2t, 2048, 256);
    k_cast_bf16<<<(262144 / 4 + 255) / 256, 256, 0, stream>>>(Wih, Wihb, 262144 / 4);
    k_cast_bf16<<<(262144 / 4 + 255) / 256, 256, 0, stream>>>(Whh, Whhb, 262144 / 4);
    k_cast_bf16<<<(9472000 / 4 + 255) / 256, 256, 0, stream>>>(Wp, Wpb, 9472000 / 4);
    k_add2<<<4, 256, 0, stream>>>(bih, bhh, bb, 1024);

    // CSR
    k_deg_init<<<NN / 256, 256, 0, stream>>>(deg);
    k_deg_count<<<NE / 256, 256, 0, stream>>>(ei, deg);
    k_scan<<<1, 1024, 0, stream>>>(deg, row_start, cursor);
    k_fill<<<(NTOT + 255) / 256, 256, 0, stream>>>(ei, cursor, csr_src);

    // embedding gather
    k_gather_x<<<NN * 64 / 256, 256, 0, stream>>>(x_ids, emb, xb);

    // GAT layer 1
    k_gemm_bt<true, false><<<dim3(NN / 128, 2048 / 128), 256, 0, stream>>>(
        xb, W1t, h1b, nullptr, NN, 2048, 256);
    k_alpha1<<<NN, 256, 0, stream>>>(h1b, as1w, ad1w, als1, ald1);
    k_agg1<<<NN, 256, 0, stream>>>(row_start, csr_src, als1, ald1, h1b, b1, out1b);

    // GAT layer 2
    k_gemm_bt<true, false><<<dim3(NN / 128, 256 / 128), 256, 0, stream>>>(
        out1b, W2t, x2b, nullptr, NN, 256, 2048);
    k_alpha2<<<NN, 64, 0, stream>>>(x2b, as2w, ad2w, als2, ald2);
    k_agg2<<<NN, 64, 0, stream>>>(row_start, csr_src, als2, ald2, x2b, b2, out2b);

    // LSTM: Xg = out2 @ Wih^T + (bih + bhh)
    k_gemm_bt<false, true><<<dim3(NN / 128, 1024 / 128), 256, 0, stream>>>(
        out2b, Wihb, Xg, bb, NN, 1024, 256);
    k_lstm4<<<16, 1024, 0, stream>>>(Xg, Whhb, hTb);

    // final projection
    k_gemm_bt<false, true><<<dim3(256 / 128, (37000 + 127) / 128), 256, 0, stream>>>(
        hTb, Wpb, (float*)d_out, bp, 256, 37000, 256);
}

// Round 5
// 808.655 us; speedup vs baseline: 1.2522x; 1.2522x over previous
//
#include <hip/hip_runtime.h>
#include <hip/hip_bf16.h>
#include <cstdint>

#define HD 256
#define NHEADS 8
#define NB 256
#define SL 64
#define NN 16384
#define NE 131072
#define NTOT (NE + NN)   // 147456

typedef float floatx4 __attribute__((ext_vector_type(4)));
typedef short shortx8 __attribute__((ext_vector_type(8)));
typedef unsigned short ushortx8 __attribute__((ext_vector_type(8)));
typedef unsigned short ushortx4 __attribute__((ext_vector_type(4)));

__device__ __forceinline__ unsigned short f2bf(float f) {
    union { float f; unsigned u; } a; a.f = f;
    unsigned r = a.u + 0x7fffu + ((a.u >> 16) & 1u);
    return (unsigned short)(r >> 16);
}
__device__ __forceinline__ float bf2f(unsigned short b) {
    union { unsigned u; float f; } a; a.u = ((unsigned)b) << 16;
    return a.f;
}

// ---------------- conversions ----------------

__global__ void k_cast_bf16(const float* __restrict__ in, unsigned short* __restrict__ out, int n4) {
    int i = blockIdx.x * 256 + threadIdx.x;
    if (i >= n4) return;
    float4 v = ((const float4*)in)[i];
    ushortx4 o;
    o[0] = f2bf(v.x); o[1] = f2bf(v.y); o[2] = f2bf(v.z); o[3] = f2bf(v.w);
    *(ushortx4*)&out[i * 4] = o;
}

// out[n][k] = bf16(in[k][n]); in is K x N fp32. grid (N/32, K/32), block (32,8)
__global__ void k_transpose_bf16(const float* __restrict__ in, unsigned short* __restrict__ out,
                                 int K, int N) {
    __shared__ float t[32][33];
    int nb = blockIdx.x * 32, kb = blockIdx.y * 32;
    int tx = threadIdx.x, ty = threadIdx.y;
#pragma unroll
    for (int i = 0; i < 4; ++i) {
        int k = kb + ty + i * 8;
        t[ty + i * 8][tx] = in[(size_t)k * N + nb + tx];
    }
    __syncthreads();
#pragma unroll
    for (int i = 0; i < 4; ++i) {
        int nrow = nb + ty + i * 8;
        out[(size_t)nrow * K + kb + tx] = f2bf(t[tx][ty + i * 8]);
    }
}

__global__ void k_add2(const float* __restrict__ a, const float* __restrict__ b,
                       float* __restrict__ o, int n) {
    int i = blockIdx.x * 256 + threadIdx.x;
    if (i < n) o[i] = a[i] + b[i];
}

__global__ void k_zero(int* __restrict__ p, int n) {
    int i = blockIdx.x * 256 + threadIdx.x;
    if (i < n) p[i] = 0;
}

// x_b[n][d] = bf16(emb[x_ids[n]][d]), row 0 of emb forced to 0
__global__ void k_gather_x(const int* __restrict__ ids, const float* __restrict__ emb,
                           unsigned short* __restrict__ xb) {
    int i = blockIdx.x * 256 + threadIdx.x;   // over NN*64
    int n = i >> 6, d4 = (i & 63) << 2;
    int id = ids[n];
    float4 v = make_float4(0.f, 0.f, 0.f, 0.f);
    if (id != 0) v = *(const float4*)&emb[(size_t)id * HD + d4];
    ushortx4 o;
    o[0] = f2bf(v.x); o[1] = f2bf(v.y); o[2] = f2bf(v.z); o[3] = f2bf(v.w);
    *(ushortx4*)&xb[(size_t)n * HD + d4] = o;
}

// ---------------- GEMM: C(MxN) = A(MxK bf16) * B^T  (B given as N x K bf16) ----------------

template <bool OUT_BF16, bool HAS_BIAS>
__global__ __launch_bounds__(256, 2) void k_gemm_bt(
    const unsigned short* __restrict__ A, const unsigned short* __restrict__ B,
    void* __restrict__ C, const float* __restrict__ bias, int M, int Nn, int K) {
    constexpr int LDT = 56;
    __shared__ unsigned short As[128 * LDT];
    __shared__ unsigned short Bs[128 * LDT];
    int tid = threadIdx.x;
    int wave = tid >> 6, lane = tid & 63;
    int q = lane >> 4, c16 = lane & 15;
    long m0 = (long)blockIdx.x * 128;
    long n0 = (long)blockIdx.y * 128;
    int wm = (wave & 1) << 6, wn = (wave >> 1) << 6;
    floatx4 acc[4][4] = {};
    int lrow = tid >> 2;
    int lk = (tid & 3) << 3;
    const unsigned short* Arow0 = A + (m0 + lrow) * K + lk;
    const unsigned short* Arow1 = A + (m0 + 64 + lrow) * K + lk;
    long nb0 = n0 + lrow;      if (nb0 >= Nn) nb0 = Nn - 1;
    long nb1 = n0 + 64 + lrow; if (nb1 >= Nn) nb1 = Nn - 1;
    const unsigned short* Brow0 = B + nb0 * K + lk;
    const unsigned short* Brow1 = B + nb1 * K + lk;

    for (int k0 = 0; k0 < K; k0 += 32) {
        ushortx8 a0 = *(const ushortx8*)(Arow0 + k0);
        ushortx8 a1 = *(const ushortx8*)(Arow1 + k0);
        ushortx8 b0 = *(const ushortx8*)(Brow0 + k0);
        ushortx8 b1 = *(const ushortx8*)(Brow1 + k0);
        __syncthreads();
        *(ushortx8*)&As[lrow * LDT + lk] = a0;
        *(ushortx8*)&As[(64 + lrow) * LDT + lk] = a1;
        *(ushortx8*)&Bs[lrow * LDT + lk] = b0;
        *(ushortx8*)&Bs[(64 + lrow) * LDT + lk] = b1;
        __syncthreads();
        shortx8 af[4], bfr[4];
#pragma unroll
        for (int mt = 0; mt < 4; ++mt)
            af[mt] = *(const shortx8*)&As[(wm + mt * 16 + c16) * LDT + q * 8];
#pragma unroll
        for (int nt = 0; nt < 4; ++nt)
            bfr[nt] = *(const shortx8*)&Bs[(wn + nt * 16 + c16) * LDT + q * 8];
#pragma unroll
        for (int mt = 0; mt < 4; ++mt)
#pragma unroll
            for (int nt = 0; nt < 4; ++nt)
                acc[mt][nt] = __builtin_amdgcn_mfma_f32_16x16x32_bf16(af[mt], bfr[nt], acc[mt][nt], 0, 0, 0);
    }
#pragma unroll
    for (int mt = 0; mt < 4; ++mt) {
        long row_base = m0 + wm + mt * 16 + q * 4;
#pragma unroll
        for (int nt = 0; nt < 4; ++nt) {
            long col = n0 + wn + nt * 16 + c16;
            if (col >= Nn) continue;
            float bv = HAS_BIAS ? bias[col] : 0.0f;
#pragma unroll
            for (int r = 0; r < 4; ++r) {
                float v = acc[mt][nt][r] + bv;
                long idx = (row_base + r) * (long)Nn + col;
                if (OUT_BF16) ((unsigned short*)C)[idx] = f2bf(v);
                else          ((float*)C)[idx] = v;
            }
        }
    }
}

// ---------------- attention dots ----------------

__global__ void k_alpha1(const unsigned short* __restrict__ h1b, const float* __restrict__ asrc,
                         const float* __restrict__ adst, float* __restrict__ als,
                         float* __restrict__ ald) {
    int n = blockIdx.x, t = threadIdx.x;
    ushortx8 hv = *(const ushortx8*)&h1b[(size_t)n * 2048 + t * 8];
    float s = 0.f, d = 0.f;
#pragma unroll
    for (int j = 0; j < 8; ++j) {
        float f = bf2f(hv[j]);
        s += f * asrc[t * 8 + j];
        d += f * adst[t * 8 + j];
    }
    for (int o = 16; o; o >>= 1) { s += __shfl_down(s, o, 32); d += __shfl_down(d, o, 32); }
    if ((t & 31) == 0) { als[n * 8 + (t >> 5)] = s; ald[n * 8 + (t >> 5)] = d; }
}

__global__ void k_alpha2(const unsigned short* __restrict__ x2b, const float* __restrict__ asrc,
                         const float* __restrict__ adst, float* __restrict__ als,
                         float* __restrict__ ald) {
    int n = blockIdx.x, t = threadIdx.x;
    ushortx4 hv = *(const ushortx4*)&x2b[(size_t)n * 256 + t * 4];
    float s = 0.f, d = 0.f;
#pragma unroll
    for (int j = 0; j < 4; ++j) {
        float f = bf2f(hv[j]);
        s += f * asrc[t * 4 + j];
        d += f * adst[t * 4 + j];
    }
    for (int o = 32; o; o >>= 1) { s += __shfl_down(s, o, 64); d += __shfl_down(d, o, 64); }
    if (t == 0) { als[n] = s; ald[n] = d; }
}

// ---------------- CSR build ----------------

__global__ void k_deg_init(int* __restrict__ deg) {
    int i = blockIdx.x * 256 + threadIdx.x;
    if (i < NN) deg[i] = 1;
}
__global__ void k_deg_count(const int* __restrict__ ei, int* __restrict__ deg) {
    int e = blockIdx.x * 256 + threadIdx.x;
    if (e < NE) atomicAdd(&deg[ei[NE + e]], 1);
}
__global__ void k_scan(const int* __restrict__ deg, int* __restrict__ row_start,
                       int* __restrict__ cursor) {
    __shared__ int s[1024];
    int t = threadIdx.x;
    int base = t * 16;
    int loc[16]; int sum = 0;
#pragma unroll
    for (int i = 0; i < 16; ++i) { loc[i] = deg[base + i]; sum += loc[i]; }
    s[t] = sum;
    __syncthreads();
    for (int o = 1; o < 1024; o <<= 1) {
        int v = (t >= o) ? s[t - o] : 0;
        __syncthreads();
        s[t] += v;
        __syncthreads();
    }
    int ex = s[t] - sum;
#pragma unroll
    for (int i = 0; i < 16; ++i) {
        row_start[base + i] = ex;
        cursor[base + i] = ex;
        ex += loc[i];
    }
    if (t == 0) row_start[NN] = NTOT;
}
__global__ void k_fill(const int* __restrict__ ei, int* __restrict__ cursor,
                       int* __restrict__ csr_src) {
    int e = blockIdx.x * 256 + threadIdx.x;
    if (e >= NTOT) return;
    int s, d;
    if (e < NE) { s = ei[e]; d = ei[NE + e]; }
    else        { s = e - NE; d = s; }
    int p = atomicAdd(&cursor[d], 1);
    csr_src[p] = s;
}

// ---------------- GAT aggregation ----------------

__global__ __launch_bounds__(256) void k_agg1(
    const int* __restrict__ row_start, const int* __restrict__ csr_src,
    const float* __restrict__ als, const float* __restrict__ ald,
    const unsigned short* __restrict__ h1b, const float* __restrict__ b1,
    unsigned short* __restrict__ out1b) {
    int n = blockIdx.x, t = threadIdx.x;
    int rs = row_start[n];
    int deg = row_start[n + 1] - rs;
    __shared__ float sm[8], sz[8], sad[8];
    if (t < 8) sad[t] = ald[n * 8 + t];
    __syncthreads();
    int hh = t >> 5, ii = t & 31;
    float adh = sad[hh];
    float lm = -1e30f;
    for (int i = ii; i < deg; i += 32) {
        int s = csr_src[rs + i];
        float e = als[s * 8 + hh] + adh;
        e = e >= 0.f ? e : 0.2f * e;
        lm = fmaxf(lm, e);
    }
    for (int o = 16; o; o >>= 1) lm = fmaxf(lm, __shfl_down(lm, o, 32));
    if (ii == 0) sm[hh] = lm;
    __syncthreads();
    float mh = sm[hh];
    float lz = 0.f;
    for (int i = ii; i < deg; i += 32) {
        int s = csr_src[rs + i];
        float e = als[s * 8 + hh] + adh;
        e = e >= 0.f ? e : 0.2f * e;
        lz += expf(e - mh);
    }
    for (int o = 16; o; o >>= 1) lz += __shfl_down(lz, o, 32);
    if (ii == 0) sz[hh] = lz;
    __syncthreads();
    float inv_z = 1.0f / (sz[hh] + 1e-16f);
    float acc[8] = {0.f, 0.f, 0.f, 0.f, 0.f, 0.f, 0.f, 0.f};
    for (int i = 0; i < deg; ++i) {
        int s = csr_src[rs + i];
        float e = als[s * 8 + hh] + adh;
        e = e >= 0.f ? e : 0.2f * e;
        float w = expf(e - mh) * inv_z;
        ushortx8 hv = *(const ushortx8*)&h1b[(size_t)s * 2048 + t * 8];
#pragma unroll
        for (int j = 0; j < 8; ++j) acc[j] += w * bf2f(hv[j]);
    }
    ushortx8 o8;
#pragma unroll
    for (int j = 0; j < 8; ++j) {
        float v = acc[j] + b1[t * 8 + j];
        v = v > 0.f ? v : expm1f(v);
        o8[j] = f2bf(v);
    }
    *(ushortx8*)&out1b[(size_t)n * 2048 + t * 8] = o8;
}

__global__ void k_agg2(const int* __restrict__ row_start, const int* __restrict__ csr_src,
                       const float* __restrict__ als, const float* __restrict__ ald,
                       const unsigned short* __restrict__ x2b, const float* __restrict__ b2,
                       unsigned short* __restrict__ out2b) {
    int n = blockIdx.x, t = threadIdx.x;
    int rs = row_start[n];
    int deg = row_start[n + 1] - rs;
    float adn = ald[n];
    float lm = -1e30f;
    for (int i = t; i < deg; i += 64) {
        float e = als[csr_src[rs + i]] + adn;
        e = e >= 0.f ? e : 0.2f * e;
        lm = fmaxf(lm, e);
    }
    for (int o = 32; o; o >>= 1) lm = fmaxf(lm, __shfl_down(lm, o, 64));
    float mh = __shfl(lm, 0, 64);
    float lz = 0.f;
    for (int i = t; i < deg; i += 64) {
        float e = als[csr_src[rs + i]] + adn;
        e = e >= 0.f ? e : 0.2f * e;
        lz += expf(e - mh);
    }
    for (int o = 32; o; o >>= 1) lz += __shfl_down(lz, o, 64);
    float zz = __shfl(lz, 0, 64);
    float inv_z = 1.0f / (zz + 1e-16f);
    float acc[4] = {0.f, 0.f, 0.f, 0.f};
    for (int i = 0; i < deg; ++i) {
        int s = csr_src[rs + i];
        float e = als[s] + adn;
        e = e >= 0.f ? e : 0.2f * e;
        float w = expf(e - mh) * inv_z;
        ushortx4 hv = *(const ushortx4*)&x2b[(size_t)s * 256 + t * 4];
#pragma unroll
        for (int j = 0; j < 4; ++j) acc[j] += w * bf2f(hv[j]);
    }
    ushortx4 o4;
#pragma unroll
    for (int j = 0; j < 4; ++j) o4[j] = f2bf(acc[j] + b2[t * 4 + j]);
    *(ushortx4*)&out2b[(size_t)n * 256 + t * 4] = o4;
}

// ---------------- LSTM weight repack for k_lstm7 ----------------
// WhhR frag layout: frag id F = ((s*4 + w)*8 + k0)*4 + f  (s=col-slice, w=wave,
// k0=K-chunk, f=gate). Within a frag: 64 lanes x 8 bf16 (16B) in lane order, so a
// wave's ds_write/ds_read at lane*16 is linear and conflict-free.
// Source element: gate-col = f*256 + s*64 + w*16 + c16, k = k0*32 + q*8.
__global__ void k_repack_whh(const unsigned short* __restrict__ Whhb,
                             unsigned short* __restrict__ WhhR) {
    int i = blockIdx.x * 256 + threadIdx.x;    // 32768 threads = 512 frags x 64 lanes
    int lane = i & 63;
    int fi = i >> 6;                            // 0..511
    int f = fi & 3, k0 = (fi >> 2) & 7, w = (fi >> 5) & 3, s = fi >> 7;
    int q = lane >> 4, c16 = lane & 15;
    int gcol = f * 256 + s * 64 + w * 16 + c16;
    int k = k0 * 32 + q * 8;
    ushortx8 v = *(const ushortx8*)&Whhb[(size_t)gcol * 256 + k];
    *(ushortx8*)&WhhR[(size_t)fi * 512 + lane * 8] = v;
}

// ---------------- LSTM recurrence, v7: LDS-resident weights + v2-PROVEN sync ----------------
// Structure identical to v6 (64 blocks = 16 batch-groups x 4 col-slices; 128KB Whh
// slice preloaded to LDS once; zero per-step weight traffic; cross-block h exchange
// through global ring hX[t] with per-(group,step) flag counters).
// v6 -> v7 sync hardening (v6's bench died; the only unproven construct was the
// relaxed-atomic protocol):
//  - spin load is ACQUIRE at agent scope (the exact encoding HW-proven in v2; a
//    relaxed agent load that fails to bypass the non-coherent per-XCD L2 would
//    spin on a stale line forever = the suspected hang),
//  - producer publishes with a single RELEASE fetch_add after __syncthreads
//    (release RMW emits the L2 writeback; v2-proven encoding),
//  - spin is BOUNDED (65536 polls ~ 15ms): a protocol stall now ends the kernel
//    with wrong data (-> absmax + counters for diagnosis) instead of a GPU hang.
// Per-poll acquire invalidates are cheap here because weights are in LDS (immune);
// h/Xg need fresh lines anyway. That was v2's hidden cost, structurally gone.

__global__ __launch_bounds__(256, 1) void k_lstm7(
    const float* __restrict__ Xg, const unsigned short* __restrict__ WhhR,
    unsigned short* __restrict__ hX, int* __restrict__ flags) {
    __shared__ unsigned short wlds[4 * 32 * 512];   // 128KB: [wave][k0*4+f][lane*8]

    int tid = threadIdx.x;
    int w = tid >> 6, lane = tid & 63;
    int q = lane >> 4, c16 = lane & 15;
    int g = blockIdx.x & 15, s = blockIdx.x >> 4;
    int scol = s * 64 + w * 16 + c16;               // h-col this lane owns
    const int fbase = g * 64;

    // one-time preload of this wave's 32 weight frags (32KB) into LDS
    const unsigned short* wsrc = WhhR + (size_t)((s * 4 + w) * 32) * 512 + lane * 8;
#pragma unroll
    for (int fi = 0; fi < 32; ++fi)
        *(shortx8*)&wlds[(w * 32 + fi) * 512 + lane * 8] =
            *(const shortx8*)(wsrc + fi * 512);

    float cst[4] = {0.f, 0.f, 0.f, 0.f};

    for (int t = 0; t < SL; ++t) {
        // Xg prefetch: issued before the spin so its latency hides under the wait
        float xg[4][4];
#pragma unroll
        for (int r = 0; r < 4; ++r) {
            const float* xp = Xg + ((size_t)(g * 16 + q * 4 + r) * SL + t) * 1024 + scol;
#pragma unroll
            for (int f = 0; f < 4; ++f) xg[r][f] = xp[f * 256];
        }

        floatx4 acc[4] = {};
        if (t > 0) {
            // wait for all 4 col-slice blocks of this group to publish h[t-1]
            if (tid == 0) {
                int spins = 0;
                while (__hip_atomic_load(&flags[fbase + t - 1], __ATOMIC_ACQUIRE,
                                         __HIP_MEMORY_SCOPE_AGENT) < 4) {
                    __builtin_amdgcn_s_sleep(2);
                    if (++spins > 65536) break;   // safety: stall -> wrong data, not a hang
                }
            }
            __syncthreads();
            __builtin_amdgcn_fence(__ATOMIC_ACQUIRE, "agent");   // order h loads for all waves

            // A-frags: h[t-1], rows g*16+c16 (own batch rows), k over ALL 256 h-cols
            const unsigned short* hp =
                hX + ((size_t)(t - 1) * 256 + g * 16 + c16) * 256 + q * 8;
            shortx8 af[8];
#pragma unroll
            for (int k0 = 0; k0 < 8; ++k0) af[k0] = *(const shortx8*)(hp + k0 * 32);
#pragma unroll
            for (int k0 = 0; k0 < 8; ++k0)
#pragma unroll
                for (int f = 0; f < 4; ++f) {
                    shortx8 b = *(const shortx8*)&wlds[(w * 32 + k0 * 4 + f) * 512 + lane * 8];
                    acc[f] = __builtin_amdgcn_mfma_f32_16x16x32_bf16(af[k0], b, acc[f], 0, 0, 0);
                }
        }

        // epilogue: gates -> c,h for rows q*4+r, col scol
        unsigned short* hw = hX + ((size_t)t * 256 + g * 16) * 256 + scol;
#pragma unroll
        for (int r = 0; r < 4; ++r) {
            float gi = acc[0][r] + xg[r][0];
            float gf = acc[1][r] + xg[r][1];
            float gG = acc[2][r] + xg[r][2];
            float go = acc[3][r] + xg[r][3];
            float si = __builtin_amdgcn_rcpf(1.f + __expf(-gi));
            float sf = __builtin_amdgcn_rcpf(1.f + __expf(-gf));
            float so = __builtin_amdgcn_rcpf(1.f + __expf(-go));
            float tg = 1.f - 2.f * __builtin_amdgcn_rcpf(1.f + __expf(2.f * gG));
            float c = sf * cst[r] + si * tg;
            cst[r] = c;
            float tc = 1.f - 2.f * __builtin_amdgcn_rcpf(1.f + __expf(2.f * c));
            hw[(q * 4 + r) * 256] = f2bf(so * tc);
        }

        if (t < SL - 1) {
            __syncthreads();   // drains every wave's h stores (vmcnt 0 before s_barrier)
            if (tid == 0)
                __hip_atomic_fetch_add(&flags[fbase + t], 1, __ATOMIC_RELEASE,
                                       __HIP_MEMORY_SCOPE_AGENT);   // v2-proven publish
        }
    }
}

// ---------------- launch ----------------

extern "C" void kernel_launch(void* const* d_in, const int* in_sizes, int n_in,
                              void* d_out, int out_size, void* d_ws, size_t ws_size,
                              hipStream_t stream) {
    const int*   x_ids = (const int*)d_in[0];
    const int*   ei    = (const int*)d_in[1];
    const float* emb   = (const float*)d_in[3];
    const float* W1    = (const float*)d_in[4];
    const float* as1w  = (const float*)d_in[5];
    const float* ad1w  = (const float*)d_in[6];
    const float* b1    = (const float*)d_in[7];
    const float* W2    = (const float*)d_in[8];
    const float* as2w  = (const float*)d_in[9];
    const float* ad2w  = (const float*)d_in[10];
    const float* b2    = (const float*)d_in[11];
    const float* Wih   = (const float*)d_in[12];
    const float* Whh   = (const float*)d_in[13];
    const float* bih   = (const float*)d_in[14];
    const float* bhh   = (const float*)d_in[15];
    const float* Wp    = (const float*)d_in[16];
    const float* bp    = (const float*)d_in[17];

    char* ws = (char*)d_ws;
    size_t off = 0;
    auto alloc = [&](size_t bytes) -> void* {
        void* p = ws + off;
        off += (bytes + 255) & ~(size_t)255;
        return p;
    };
    unsigned short* h1b   = (unsigned short*)alloc((size_t)NN * 2048 * 2);  // reused as Xg
    float*          Xg    = (float*)h1b;
    unsigned short* out1b = (unsigned short*)alloc((size_t)NN * 2048 * 2);  // reused as hX
    unsigned short* hX    = out1b;   // h ring [64][256][256] bf16 (out1b dead by LSTM time)
    unsigned short* xb    = (unsigned short*)alloc((size_t)NN * 256 * 2);
    unsigned short* x2b   = (unsigned short*)alloc((size_t)NN * 256 * 2);
    unsigned short* out2b = (unsigned short*)alloc((size_t)NN * 256 * 2);
    unsigned short* W1t   = (unsigned short*)alloc((size_t)2048 * 256 * 2);
    unsigned short* W2t   = (unsigned short*)alloc((size_t)256 * 2048 * 2);
    unsigned short* Wihb  = (unsigned short*)alloc((size_t)1024 * 256 * 2);
    unsigned short* Whhb  = (unsigned short*)alloc((size_t)1024 * 256 * 2);
    unsigned short* WhhR  = (unsigned short*)alloc((size_t)1024 * 256 * 2);
    unsigned short* Wpb   = (unsigned short*)alloc((size_t)37000 * 256 * 2);
    float*          bb    = (float*)alloc(1024 * 4);
    float*          als1  = (float*)alloc((size_t)NN * 8 * 4);
    float*          ald1  = (float*)alloc((size_t)NN * 8 * 4);
    float*          als2  = (float*)alloc((size_t)NN * 4);
    float*          ald2  = (float*)alloc((size_t)NN * 4);
    int* deg       = (int*)alloc((size_t)NN * 4);
    int* row_start = (int*)alloc((size_t)(NN + 1) * 4);
    int* cursor    = (int*)alloc((size_t)NN * 4);
    int* csr_src   = (int*)alloc((size_t)NTOT * 4);
    int* flags     = (int*)alloc((size_t)16 * 64 * 4);   // per (group, step) counters
    (void)ws_size; (void)in_sizes; (void)n_in; (void)out_size;

    // weight prep
    k_transpose_bf16<<<dim3(2048 / 32, 256 / 32), dim3(32, 8), 0, stream>>>(W1, W1t, 256, 2048);
    k_transpose_bf16<<<dim3(256 / 32, 2048 / 32), dim3(32, 8), 0, stream>>>(W2, W2t, 2048, 256);
    k_cast_bf16<<<(262144 / 4 + 255) / 256, 256, 0, stream>>>(Wih, Wihb, 262144 / 4);
    k_cast_bf16<<<(262144 / 4 + 255) / 256, 256, 0, stream>>>(Whh, Whhb, 262144 / 4);
    k_cast_bf16<<<(9472000 / 4 + 255) / 256, 256, 0, stream>>>(Wp, Wpb, 9472000 / 4);
    k_add2<<<4, 256, 0, stream>>>(bih, bhh, bb, 1024);
    k_repack_whh<<<32768 / 256, 256, 0, stream>>>(Whhb, WhhR);
    k_zero<<<4, 256, 0, stream>>>(flags, 1024);   // re-zeroed every launch (graph replay)

    // CSR
    k_deg_init<<<NN / 256, 256, 0, stream>>>(deg);
    k_deg_count<<<NE / 256, 256, 0, stream>>>(ei, deg);
    k_scan<<<1, 1024, 0, stream>>>(deg, row_start, cursor);
    k_fill<<<(NTOT + 255) / 256, 256, 0, stream>>>(ei, cursor, csr_src);

    // embedding gather
    k_gather_x<<<NN * 64 / 256, 256, 0, stream>>>(x_ids, emb, xb);

    // GAT layer 1
    k_gemm_bt<true, false><<<dim3(NN / 128, 2048 / 128), 256, 0, stream>>>(
        xb, W1t, h1b, nullptr, NN, 2048, 256);
    k_alpha1<<<NN, 256, 0, stream>>>(h1b, as1w, ad1w, als1, ald1);
    k_agg1<<<NN, 256, 0, stream>>>(row_start, csr_src, als1, ald1, h1b, b1, out1b);

    // GAT layer 2
    k_gemm_bt<true, false><<<dim3(NN / 128, 256 / 128), 256, 0, stream>>>(
        out1b, W2t, x2b, nullptr, NN, 256, 2048);
    k_alpha2<<<NN, 64, 0, stream>>>(x2b, as2w, ad2w, als2, ald2);
    k_agg2<<<NN, 64, 0, stream>>>(row_start, csr_src, als2, ald2, x2b, b2, out2b);

    // LSTM: Xg = out2 @ Wih^T + (bih + bhh)  (into dead h1b; hX aliases dead out1b)
    k_gemm_bt<false, true><<<dim3(NN / 128, 1024 / 128), 256, 0, stream>>>(
        out2b, Wihb, Xg, bb, NN, 1024, 256);
    k_lstm7<<<64, 256, 0, stream>>>(Xg, WhhR, hX, flags);

    // final projection: A = h at t=63, laid out [256][256] bf16 row-major
    k_gemm_bt<false, true><<<dim3(256 / 128, (37000 + 127) / 128), 256, 0, stream>>>(
        hX + (size_t)63 * 256 * 256, Wpb, (float*)d_out, bp, 256, 37000, 256);
}

// Round 6
// 649.830 us; speedup vs baseline: 1.5583x; 1.2444x over previous
//
#include <hip/hip_runtime.h>
#include <hip/hip_bf16.h>
#include <cstdint>

#define HD 256
#define NHEADS 8
#define NB 256
#define SL 64
#define NN 16384
#define NE 131072
#define NTOT (NE + NN)   // 147456

typedef float floatx4 __attribute__((ext_vector_type(4)));
typedef short shortx8 __attribute__((ext_vector_type(8)));
typedef unsigned short ushortx8 __attribute__((ext_vector_type(8)));
typedef unsigned short ushortx4 __attribute__((ext_vector_type(4)));

__device__ __forceinline__ unsigned short f2bf(float f) {
    union { float f; unsigned u; } a; a.f = f;
    unsigned r = a.u + 0x7fffu + ((a.u >> 16) & 1u);
    return (unsigned short)(r >> 16);
}
__device__ __forceinline__ float bf2f(unsigned short b) {
    union { unsigned u; float f; } a; a.u = ((unsigned)b) << 16;
    return a.f;
}

// system-coherent (write-through / cache-bypass) accessors for cross-block h exchange.
// sc0 sc1 => the access is performed at the coherence point (L3/IC); nothing is left
// dirty in (or served stale from) the per-XCD L2, so NO buffer_wbl2/buffer_inv walks
// are ever needed -- those walks were v7's 13.6k cy/step cost.
__device__ __forceinline__ void store_b16_sys(unsigned short* p, unsigned v) {
    asm volatile("global_store_short %0, %1, off sc0 sc1" :: "v"(p), "v"(v) : "memory");
}
__device__ __forceinline__ shortx8 load_b128_sys(const unsigned short* p) {
    shortx8 r;
    asm volatile("global_load_dwordx4 %0, %1, off sc0 sc1" : "=v"(r) : "v"(p) : "memory");
    return r;
}

// ---------------- conversions ----------------

__global__ void k_cast_bf16(const float* __restrict__ in, unsigned short* __restrict__ out, int n4) {
    int i = blockIdx.x * 256 + threadIdx.x;
    if (i >= n4) return;
    float4 v = ((const float4*)in)[i];
    ushortx4 o;
    o[0] = f2bf(v.x); o[1] = f2bf(v.y); o[2] = f2bf(v.z); o[3] = f2bf(v.w);
    *(ushortx4*)&out[i * 4] = o;
}

// out[n][k] = bf16(in[k][n]); in is K x N fp32. grid (N/32, K/32), block (32,8)
__global__ void k_transpose_bf16(const float* __restrict__ in, unsigned short* __restrict__ out,
                                 int K, int N) {
    __shared__ float t[32][33];
    int nb = blockIdx.x * 32, kb = blockIdx.y * 32;
    int tx = threadIdx.x, ty = threadIdx.y;
#pragma unroll
    for (int i = 0; i < 4; ++i) {
        int k = kb + ty + i * 8;
        t[ty + i * 8][tx] = in[(size_t)k * N + nb + tx];
    }
    __syncthreads();
#pragma unroll
    for (int i = 0; i < 4; ++i) {
        int nrow = nb + ty + i * 8;
        out[(size_t)nrow * K + kb + tx] = f2bf(t[tx][ty + i * 8]);
    }
}

__global__ void k_add2(const float* __restrict__ a, const float* __restrict__ b,
                       float* __restrict__ o, int n) {
    int i = blockIdx.x * 256 + threadIdx.x;
    if (i < n) o[i] = a[i] + b[i];
}

__global__ void k_zero(int* __restrict__ p, int n) {
    int i = blockIdx.x * 256 + threadIdx.x;
    if (i < n) p[i] = 0;
}

// x_b[n][d] = bf16(emb[x_ids[n]][d]), row 0 of emb forced to 0
__global__ void k_gather_x(const int* __restrict__ ids, const float* __restrict__ emb,
                           unsigned short* __restrict__ xb) {
    int i = blockIdx.x * 256 + threadIdx.x;   // over NN*64
    int n = i >> 6, d4 = (i & 63) << 2;
    int id = ids[n];
    float4 v = make_float4(0.f, 0.f, 0.f, 0.f);
    if (id != 0) v = *(const float4*)&emb[(size_t)id * HD + d4];
    ushortx4 o;
    o[0] = f2bf(v.x); o[1] = f2bf(v.y); o[2] = f2bf(v.z); o[3] = f2bf(v.w);
    *(ushortx4*)&xb[(size_t)n * HD + d4] = o;
}

// ---------------- GEMM: C(MxN) = A(MxK bf16) * B^T  (B given as N x K bf16) ----------------

template <bool OUT_BF16, bool HAS_BIAS>
__global__ __launch_bounds__(256, 2) void k_gemm_bt(
    const unsigned short* __restrict__ A, const unsigned short* __restrict__ B,
    void* __restrict__ C, const float* __restrict__ bias, int M, int Nn, int K) {
    constexpr int LDT = 56;
    __shared__ unsigned short As[128 * LDT];
    __shared__ unsigned short Bs[128 * LDT];
    int tid = threadIdx.x;
    int wave = tid >> 6, lane = tid & 63;
    int q = lane >> 4, c16 = lane & 15;
    long m0 = (long)blockIdx.x * 128;
    long n0 = (long)blockIdx.y * 128;
    int wm = (wave & 1) << 6, wn = (wave >> 1) << 6;
    floatx4 acc[4][4] = {};
    int lrow = tid >> 2;
    int lk = (tid & 3) << 3;
    const unsigned short* Arow0 = A + (m0 + lrow) * K + lk;
    const unsigned short* Arow1 = A + (m0 + 64 + lrow) * K + lk;
    long nb0 = n0 + lrow;      if (nb0 >= Nn) nb0 = Nn - 1;
    long nb1 = n0 + 64 + lrow; if (nb1 >= Nn) nb1 = Nn - 1;
    const unsigned short* Brow0 = B + nb0 * K + lk;
    const unsigned short* Brow1 = B + nb1 * K + lk;

    for (int k0 = 0; k0 < K; k0 += 32) {
        ushortx8 a0 = *(const ushortx8*)(Arow0 + k0);
        ushortx8 a1 = *(const ushortx8*)(Arow1 + k0);
        ushortx8 b0 = *(const ushortx8*)(Brow0 + k0);
        ushortx8 b1 = *(const ushortx8*)(Brow1 + k0);
        __syncthreads();
        *(ushortx8*)&As[lrow * LDT + lk] = a0;
        *(ushortx8*)&As[(64 + lrow) * LDT + lk] = a1;
        *(ushortx8*)&Bs[lrow * LDT + lk] = b0;
        *(ushortx8*)&Bs[(64 + lrow) * LDT + lk] = b1;
        __syncthreads();
        shortx8 af[4], bfr[4];
#pragma unroll
        for (int mt = 0; mt < 4; ++mt)
            af[mt] = *(const shortx8*)&As[(wm + mt * 16 + c16) * LDT + q * 8];
#pragma unroll
        for (int nt = 0; nt < 4; ++nt)
            bfr[nt] = *(const shortx8*)&Bs[(wn + nt * 16 + c16) * LDT + q * 8];
#pragma unroll
        for (int mt = 0; mt < 4; ++mt)
#pragma unroll
            for (int nt = 0; nt < 4; ++nt)
                acc[mt][nt] = __builtin_amdgcn_mfma_f32_16x16x32_bf16(af[mt], bfr[nt], acc[mt][nt], 0, 0, 0);
    }
#pragma unroll
    for (int mt = 0; mt < 4; ++mt) {
        long row_base = m0 + wm + mt * 16 + q * 4;
#pragma unroll
        for (int nt = 0; nt < 4; ++nt) {
            long col = n0 + wn + nt * 16 + c16;
            if (col >= Nn) continue;
            float bv = HAS_BIAS ? bias[col] : 0.0f;
#pragma unroll
            for (int r = 0; r < 4; ++r) {
                float v = acc[mt][nt][r] + bv;
                long idx = (row_base + r) * (long)Nn + col;
                if (OUT_BF16) ((unsigned short*)C)[idx] = f2bf(v);
                else          ((float*)C)[idx] = v;
            }
        }
    }
}

// ---------------- attention dots ----------------

__global__ void k_alpha1(const unsigned short* __restrict__ h1b, const float* __restrict__ asrc,
                         const float* __restrict__ adst, float* __restrict__ als,
                         float* __restrict__ ald) {
    int n = blockIdx.x, t = threadIdx.x;
    ushortx8 hv = *(const ushortx8*)&h1b[(size_t)n * 2048 + t * 8];
    float s = 0.f, d = 0.f;
#pragma unroll
    for (int j = 0; j < 8; ++j) {
        float f = bf2f(hv[j]);
        s += f * asrc[t * 8 + j];
        d += f * adst[t * 8 + j];
    }
    for (int o = 16; o; o >>= 1) { s += __shfl_down(s, o, 32); d += __shfl_down(d, o, 32); }
    if ((t & 31) == 0) { als[n * 8 + (t >> 5)] = s; ald[n * 8 + (t >> 5)] = d; }
}

__global__ void k_alpha2(const unsigned short* __restrict__ x2b, const float* __restrict__ asrc,
                         const float* __restrict__ adst, float* __restrict__ als,
                         float* __restrict__ ald) {
    int n = blockIdx.x, t = threadIdx.x;
    ushortx4 hv = *(const ushortx4*)&x2b[(size_t)n * 256 + t * 4];
    float s = 0.f, d = 0.f;
#pragma unroll
    for (int j = 0; j < 4; ++j) {
        float f = bf2f(hv[j]);
        s += f * asrc[t * 4 + j];
        d += f * adst[t * 4 + j];
    }
    for (int o = 32; o; o >>= 1) { s += __shfl_down(s, o, 64); d += __shfl_down(d, o, 64); }
    if (t == 0) { als[n] = s; ald[n] = d; }
}

// ---------------- CSR build ----------------

__global__ void k_deg_init(int* __restrict__ deg) {
    int i = blockIdx.x * 256 + threadIdx.x;
    if (i < NN) deg[i] = 1;
}
__global__ void k_deg_count(const int* __restrict__ ei, int* __restrict__ deg) {
    int e = blockIdx.x * 256 + threadIdx.x;
    if (e < NE) atomicAdd(&deg[ei[NE + e]], 1);
}
__global__ void k_scan(const int* __restrict__ deg, int* __restrict__ row_start,
                       int* __restrict__ cursor) {
    __shared__ int s[1024];
    int t = threadIdx.x;
    int base = t * 16;
    int loc[16]; int sum = 0;
#pragma unroll
    for (int i = 0; i < 16; ++i) { loc[i] = deg[base + i]; sum += loc[i]; }
    s[t] = sum;
    __syncthreads();
    for (int o = 1; o < 1024; o <<= 1) {
        int v = (t >= o) ? s[t - o] : 0;
        __syncthreads();
        s[t] += v;
        __syncthreads();
    }
    int ex = s[t] - sum;
#pragma unroll
    for (int i = 0; i < 16; ++i) {
        row_start[base + i] = ex;
        cursor[base + i] = ex;
        ex += loc[i];
    }
    if (t == 0) row_start[NN] = NTOT;
}
__global__ void k_fill(const int* __restrict__ ei, int* __restrict__ cursor,
                       int* __restrict__ csr_src) {
    int e = blockIdx.x * 256 + threadIdx.x;
    if (e >= NTOT) return;
    int s, d;
    if (e < NE) { s = ei[e]; d = ei[NE + e]; }
    else        { s = e - NE; d = s; }
    int p = atomicAdd(&cursor[d], 1);
    csr_src[p] = s;
}

// ---------------- GAT aggregation ----------------

__global__ __launch_bounds__(256) void k_agg1(
    const int* __restrict__ row_start, const int* __restrict__ csr_src,
    const float* __restrict__ als, const float* __restrict__ ald,
    const unsigned short* __restrict__ h1b, const float* __restrict__ b1,
    unsigned short* __restrict__ out1b) {
    int n = blockIdx.x, t = threadIdx.x;
    int rs = row_start[n];
    int deg = row_start[n + 1] - rs;
    __shared__ float sm[8], sz[8], sad[8];
    if (t < 8) sad[t] = ald[n * 8 + t];
    __syncthreads();
    int hh = t >> 5, ii = t & 31;
    float adh = sad[hh];
    float lm = -1e30f;
    for (int i = ii; i < deg; i += 32) {
        int s = csr_src[rs + i];
        float e = als[s * 8 + hh] + adh;
        e = e >= 0.f ? e : 0.2f * e;
        lm = fmaxf(lm, e);
    }
    for (int o = 16; o; o >>= 1) lm = fmaxf(lm, __shfl_down(lm, o, 32));
    if (ii == 0) sm[hh] = lm;
    __syncthreads();
    float mh = sm[hh];
    float lz = 0.f;
    for (int i = ii; i < deg; i += 32) {
        int s = csr_src[rs + i];
        float e = als[s * 8 + hh] + adh;
        e = e >= 0.f ? e : 0.2f * e;
        lz += expf(e - mh);
    }
    for (int o = 16; o; o >>= 1) lz += __shfl_down(lz, o, 32);
    if (ii == 0) sz[hh] = lz;
    __syncthreads();
    float inv_z = 1.0f / (sz[hh] + 1e-16f);
    float acc[8] = {0.f, 0.f, 0.f, 0.f, 0.f, 0.f, 0.f, 0.f};
    for (int i = 0; i < deg; ++i) {
        int s = csr_src[rs + i];
        float e = als[s * 8 + hh] + adh;
        e = e >= 0.f ? e : 0.2f * e;
        float w = expf(e - mh) * inv_z;
        ushortx8 hv = *(const ushortx8*)&h1b[(size_t)s * 2048 + t * 8];
#pragma unroll
        for (int j = 0; j < 8; ++j) acc[j] += w * bf2f(hv[j]);
    }
    ushortx8 o8;
#pragma unroll
    for (int j = 0; j < 8; ++j) {
        float v = acc[j] + b1[t * 8 + j];
        v = v > 0.f ? v : expm1f(v);
        o8[j] = f2bf(v);
    }
    *(ushortx8*)&out1b[(size_t)n * 2048 + t * 8] = o8;
}

__global__ void k_agg2(const int* __restrict__ row_start, const int* __restrict__ csr_src,
                       const float* __restrict__ als, const float* __restrict__ ald,
                       const unsigned short* __restrict__ x2b, const float* __restrict__ b2,
                       unsigned short* __restrict__ out2b) {
    int n = blockIdx.x, t = threadIdx.x;
    int rs = row_start[n];
    int deg = row_start[n + 1] - rs;
    float adn = ald[n];
    float lm = -1e30f;
    for (int i = t; i < deg; i += 64) {
        float e = als[csr_src[rs + i]] + adn;
        e = e >= 0.f ? e : 0.2f * e;
        lm = fmaxf(lm, e);
    }
    for (int o = 32; o; o >>= 1) lm = fmaxf(lm, __shfl_down(lm, o, 64));
    float mh = __shfl(lm, 0, 64);
    float lz = 0.f;
    for (int i = t; i < deg; i += 64) {
        float e = als[csr_src[rs + i]] + adn;
        e = e >= 0.f ? e : 0.2f * e;
        lz += expf(e - mh);
    }
    for (int o = 32; o; o >>= 1) lz += __shfl_down(lz, o, 64);
    float zz = __shfl(lz, 0, 64);
    float inv_z = 1.0f / (zz + 1e-16f);
    float acc[4] = {0.f, 0.f, 0.f, 0.f};
    for (int i = 0; i < deg; ++i) {
        int s = csr_src[rs + i];
        float e = als[s] + adn;
        e = e >= 0.f ? e : 0.2f * e;
        float w = expf(e - mh) * inv_z;
        ushortx4 hv = *(const ushortx4*)&x2b[(size_t)s * 256 + t * 4];
#pragma unroll
        for (int j = 0; j < 4; ++j) acc[j] += w * bf2f(hv[j]);
    }
    ushortx4 o4;
#pragma unroll
    for (int j = 0; j < 4; ++j) o4[j] = f2bf(acc[j] + b2[t * 4 + j]);
    *(ushortx4*)&out2b[(size_t)n * 256 + t * 4] = o4;
}

// ---------------- LSTM weight repack for k_lstm8 ----------------
// WhhR frag layout: frag id F = ((s*4 + w)*8 + k0)*4 + f  (s=col-slice, w=wave,
// k0=K-chunk, f=gate). Within a frag: 64 lanes x 8 bf16 (16B) in lane order, so a
// wave's ds_write/ds_read at lane*16 is linear and conflict-free.
// Source element: gate-col = f*256 + s*64 + w*16 + c16, k = k0*32 + q*8.
__global__ void k_repack_whh(const unsigned short* __restrict__ Whhb,
                             unsigned short* __restrict__ WhhR) {
    int i = blockIdx.x * 256 + threadIdx.x;    // 32768 threads = 512 frags x 64 lanes
    int lane = i & 63;
    int fi = i >> 6;                            // 0..511
    int f = fi & 3, k0 = (fi >> 2) & 7, w = (fi >> 5) & 3, s = fi >> 7;
    int q = lane >> 4, c16 = lane & 15;
    int gcol = f * 256 + s * 64 + w * 16 + c16;
    int k = k0 * 32 + q * 8;
    ushortx8 v = *(const ushortx8*)&Whhb[(size_t)gcol * 256 + k];
    *(ushortx8*)&WhhR[(size_t)fi * 512 + lane * 8] = v;
}

// ---------------- LSTM recurrence, v8: LDS weights + fence-free sc1 exchange ----------------
// Topology of v7 (64 blocks = 16 batch-groups x 4 col-slices; 128KB Whh slice in
// LDS, loaded once; h exchanged through global ring hX[t] + flag counters).
// v7 post-mortem: 13.6k cy/step came from cache-MAINTENANCE walks -- every ACQUIRE
// poll emitted buffer_inv (L2 tag walk) and every RELEASE fetch_add emitted
// buffer_wbl2 (L2 writeback walk), serialized across the 8 blocks of each XCD.
// (v6's hang showed the complement: a RELAXED agent *load* does NOT bypass stale L2.)
// v8 removes every maintenance op from the loop (AITER/RCCL-style hand protocol):
//  - h stores:  asm global_store_short sc0 sc1  (write-through to L3; L2 never dirty
//               -> nothing ever needs wbl2),
//  - ordering:  explicit s_waitcnt vmcnt(0) (stores ack'd at the coherence point) +
//               __syncthreads, THEN tid0 publishes with RELAXED fetch_add (atomic
//               RMWs execute at the coherence point; no wb/inv side effects),
//  - poll:      RELAXED fetch_add(flag, 0) -- an RMW is fresh by construction (goes
//               to L3), fixing v6's stale-load hang without v7's per-poll inv,
//  - h loads:   asm global_load_dwordx4 sc0 sc1 (read L3 directly, bypass stale L2)
//               + explicit s_waitcnt vmcnt(0) + sched_barrier(0) before the MFMAs.
// Xg/weights stay normally cached; L2 is never invalidated. Bounded spin retained:
// a protocol stall ends as wrong data + counters, not a dead container.

__global__ __launch_bounds__(256, 1) void k_lstm8(
    const float* __restrict__ Xg, const unsigned short* __restrict__ WhhR,
    unsigned short* __restrict__ hX, int* __restrict__ flags) {
    __shared__ unsigned short wlds[4 * 32 * 512];   // 128KB: [wave][k0*4+f][lane*8]

    int tid = threadIdx.x;
    int w = tid >> 6, lane = tid & 63;
    int q = lane >> 4, c16 = lane & 15;
    int g = blockIdx.x & 15, s = blockIdx.x >> 4;
    int scol = s * 64 + w * 16 + c16;               // h-col this lane owns
    const int fbase = g * 64;

    // one-time preload of this wave's 32 weight frags (32KB) into LDS
    const unsigned short* wsrc = WhhR + (size_t)((s * 4 + w) * 32) * 512 + lane * 8;
#pragma unroll
    for (int fi = 0; fi < 32; ++fi)
        *(shortx8*)&wlds[(w * 32 + fi) * 512 + lane * 8] =
            *(const shortx8*)(wsrc + fi * 512);

    float cst[4] = {0.f, 0.f, 0.f, 0.f};

    for (int t = 0; t < SL; ++t) {
        // Xg prefetch: issued before the spin so its latency hides under the wait
        float xg[4][4];
#pragma unroll
        for (int r = 0; r < 4; ++r) {
            const float* xp = Xg + ((size_t)(g * 16 + q * 4 + r) * SL + t) * 1024 + scol;
#pragma unroll
            for (int f = 0; f < 4; ++f) xg[r][f] = xp[f * 256];
        }

        floatx4 acc[4] = {};
        if (t > 0) {
            // wait for all 4 col-slice blocks of this group to publish h[t-1].
            // Poll via RMW: executes at the coherence point -> always fresh, no inv.
            if (tid == 0) {
                int spins = 0;
                while (__hip_atomic_fetch_add(&flags[fbase + t - 1], 0, __ATOMIC_RELAXED,
                                              __HIP_MEMORY_SCOPE_AGENT) < 4) {
                    __builtin_amdgcn_s_sleep(2);
                    if (++spins > 65536) break;   // stall -> wrong data, not a hang
                }
            }
            __syncthreads();

            // A-frags: h[t-1], rows g*16+c16 (own batch rows), all 256 h-cols,
            // read straight from the coherence point (bypass possibly-stale L2).
            const unsigned short* hp =
                hX + ((size_t)(t - 1) * 256 + g * 16 + c16) * 256 + q * 8;
            shortx8 af[8];
#pragma unroll
            for (int k0 = 0; k0 < 8; ++k0) af[k0] = load_b128_sys(hp + k0 * 32);
            asm volatile("s_waitcnt vmcnt(0)" ::: "memory");
            __builtin_amdgcn_sched_barrier(0);
#pragma unroll
            for (int k0 = 0; k0 < 8; ++k0)
#pragma unroll
                for (int f = 0; f < 4; ++f) {
                    shortx8 b = *(const shortx8*)&wlds[(w * 32 + k0 * 4 + f) * 512 + lane * 8];
                    acc[f] = __builtin_amdgcn_mfma_f32_16x16x32_bf16(af[k0], b, acc[f], 0, 0, 0);
                }
        }

        // epilogue: gates -> c,h for rows q*4+r, col scol; h stored write-through
        unsigned short* hw = hX + ((size_t)t * 256 + g * 16) * 256 + scol;
#pragma unroll
        for (int r = 0; r < 4; ++r) {
            float gi = acc[0][r] + xg[r][0];
            float gf = acc[1][r] + xg[r][1];
            float gG = acc[2][r] + xg[r][2];
            float go = acc[3][r] + xg[r][3];
            float si = __builtin_amdgcn_rcpf(1.f + __expf(-gi));
            float sf = __builtin_amdgcn_rcpf(1.f + __expf(-gf));
            float so = __builtin_amdgcn_rcpf(1.f + __expf(-go));
            float tg = 1.f - 2.f * __builtin_amdgcn_rcpf(1.f + __expf(2.f * gG));
            float c = sf * cst[r] + si * tg;
            cst[r] = c;
            float tc = 1.f - 2.f * __builtin_amdgcn_rcpf(1.f + __expf(2.f * c));
            store_b16_sys(hw + (q * 4 + r) * 256, (unsigned)f2bf(so * tc));
        }

        if (t < SL - 1) {
            // drain write-through stores to the coherence point, then publish
            asm volatile("s_waitcnt vmcnt(0)" ::: "memory");
            __syncthreads();
            if (tid == 0)
                __hip_atomic_fetch_add(&flags[fbase + t], 1, __ATOMIC_RELAXED,
                                       __HIP_MEMORY_SCOPE_AGENT);
        }
    }
}

// ---------------- launch ----------------

extern "C" void kernel_launch(void* const* d_in, const int* in_sizes, int n_in,
                              void* d_out, int out_size, void* d_ws, size_t ws_size,
                              hipStream_t stream) {
    const int*   x_ids = (const int*)d_in[0];
    const int*   ei    = (const int*)d_in[1];
    const float* emb   = (const float*)d_in[3];
    const float* W1    = (const float*)d_in[4];
    const float* as1w  = (const float*)d_in[5];
    const float* ad1w  = (const float*)d_in[6];
    const float* b1    = (const float*)d_in[7];
    const float* W2    = (const float*)d_in[8];
    const float* as2w  = (const float*)d_in[9];
    const float* ad2w  = (const float*)d_in[10];
    const float* b2    = (const float*)d_in[11];
    const float* Wih   = (const float*)d_in[12];
    const float* Whh   = (const float*)d_in[13];
    const float* bih   = (const float*)d_in[14];
    const float* bhh   = (const float*)d_in[15];
    const float* Wp    = (const float*)d_in[16];
    const float* bp    = (const float*)d_in[17];

    char* ws = (char*)d_ws;
    size_t off = 0;
    auto alloc = [&](size_t bytes) -> void* {
        void* p = ws + off;
        off += (bytes + 255) & ~(size_t)255;
        return p;
    };
    unsigned short* h1b   = (unsigned short*)alloc((size_t)NN * 2048 * 2);  // reused as Xg
    float*          Xg    = (float*)h1b;
    unsigned short* out1b = (unsigned short*)alloc((size_t)NN * 2048 * 2);  // reused as hX
    unsigned short* hX    = out1b;   // h ring [64][256][256] bf16 (out1b dead by LSTM time)
    unsigned short* xb    = (unsigned short*)alloc((size_t)NN * 256 * 2);
    unsigned short* x2b   = (unsigned short*)alloc((size_t)NN * 256 * 2);
    unsigned short* out2b = (unsigned short*)alloc((size_t)NN * 256 * 2);
    unsigned short* W1t   = (unsigned short*)alloc((size_t)2048 * 256 * 2);
    unsigned short* W2t   = (unsigned short*)alloc((size_t)256 * 2048 * 2);
    unsigned short* Wihb  = (unsigned short*)alloc((size_t)1024 * 256 * 2);
    unsigned short* Whhb  = (unsigned short*)alloc((size_t)1024 * 256 * 2);
    unsigned short* WhhR  = (unsigned short*)alloc((size_t)1024 * 256 * 2);
    unsigned short* Wpb   = (unsigned short*)alloc((size_t)37000 * 256 * 2);
    float*          bb    = (float*)alloc(1024 * 4);
    float*          als1  = (float*)alloc((size_t)NN * 8 * 4);
    float*          ald1  = (float*)alloc((size_t)NN * 8 * 4);
    float*          als2  = (float*)alloc((size_t)NN * 4);
    float*          ald2  = (float*)alloc((size_t)NN * 4);
    int* deg       = (int*)alloc((size_t)NN * 4);
    int* row_start = (int*)alloc((size_t)(NN + 1) * 4);
    int* cursor    = (int*)alloc((size_t)NN * 4);
    int* csr_src   = (int*)alloc((size_t)NTOT * 4);
    int* flags     = (int*)alloc((size_t)16 * 64 * 4);   // per (group, step) counters
    (void)ws_size; (void)in_sizes; (void)n_in; (void)out_size;

    // weight prep
    k_transpose_bf16<<<dim3(2048 / 32, 256 / 32), dim3(32, 8), 0, stream>>>(W1, W1t, 256, 2048);
    k_transpose_bf16<<<dim3(256 / 32, 2048 / 32), dim3(32, 8), 0, stream>>>(W2, W2t, 2048, 256);
    k_cast_bf16<<<(262144 / 4 + 255) / 256, 256, 0, stream>>>(Wih, Wihb, 262144 / 4);
    k_cast_bf16<<<(262144 / 4 + 255) / 256, 256, 0, stream>>>(Whh, Whhb, 262144 / 4);
    k_cast_bf16<<<(9472000 / 4 + 255) / 256, 256, 0, stream>>>(Wp, Wpb, 9472000 / 4);
    k_add2<<<4, 256, 0, stream>>>(bih, bhh, bb, 1024);
    k_repack_whh<<<32768 / 256, 256, 0, stream>>>(Whhb, WhhR);
    k_zero<<<4, 256, 0, stream>>>(flags, 1024);   // re-zeroed every launch (graph replay)

    // CSR
    k_deg_init<<<NN / 256, 256, 0, stream>>>(deg);
    k_deg_count<<<NE / 256, 256, 0, stream>>>(ei, deg);
    k_scan<<<1, 1024, 0, stream>>>(deg, row_start, cursor);
    k_fill<<<(NTOT + 255) / 256, 256, 0, stream>>>(ei, cursor, csr_src);

    // embedding gather
    k_gather_x<<<NN * 64 / 256, 256, 0, stream>>>(x_ids, emb, xb);

    // GAT layer 1
    k_gemm_bt<true, false><<<dim3(NN / 128, 2048 / 128), 256, 0, stream>>>(
        xb, W1t, h1b, nullptr, NN, 2048, 256);
    k_alpha1<<<NN, 256, 0, stream>>>(h1b, as1w, ad1w, als1, ald1);
    k_agg1<<<NN, 256, 0, stream>>>(row_start, csr_src, als1, ald1, h1b, b1, out1b);

    // GAT layer 2
    k_gemm_bt<true, false><<<dim3(NN / 128, 256 / 128), 256, 0, stream>>>(
        out1b, W2t, x2b, nullptr, NN, 256, 2048);
    k_alpha2<<<NN, 64, 0, stream>>>(x2b, as2w, ad2w, als2, ald2);
    k_agg2<<<NN, 64, 0, stream>>>(row_start, csr_src, als2, ald2, x2b, b2, out2b);

    // LSTM: Xg = out2 @ Wih^T + (bih + bhh)  (into dead h1b; hX aliases dead out1b)
    k_gemm_bt<false, true><<<dim3(NN / 128, 1024 / 128), 256, 0, stream>>>(
        out2b, Wihb, Xg, bb, NN, 1024, 256);
    k_lstm8<<<64, 256, 0, stream>>>(Xg, WhhR, hX, flags);

    // final projection: A = h at t=63, laid out [256][256] bf16 row-major
    k_gemm_bt<false, true><<<dim3(256 / 128, (37000 + 127) / 128), 256, 0, stream>>>(
        hX + (size_t)63 * 256 * 256, Wpb, (float*)d_out, bp, 256, 37000, 256);
}